// Round 7
// baseline (1321.773 us; speedup 1.0000x reference)
//
#include <hip/hip_runtime.h>

typedef float v2f __attribute__((ext_vector_type(2)));
typedef _Float16 f16x8 __attribute__((ext_vector_type(8)));
typedef float f32x4 __attribute__((ext_vector_type(4)));

#define LOG2E 1.4426950408889634f
#define LN2   0.6931471805599453f

__device__ __forceinline__ float fexp2(float x) {
  float r; asm("v_exp_f32 %0, %1" : "=v"(r) : "v"(x)); return r;
}
__device__ __forceinline__ float frcp(float x) {
  float r; asm("v_rcp_f32 %0, %1" : "=v"(r) : "v"(x)); return r;
}
__device__ __forceinline__ float flog2(float x) {
  float r; asm("v_log_f32 %0, %1" : "=v"(r) : "v"(x)); return r;
}
// LDS-ordering-only barrier: skips the vmcnt(0) drain __syncthreads would emit,
// so prefetched pre-gate loads / hout stores stay in flight across step barriers.
__device__ __forceinline__ void lgkm_barrier() {
  __builtin_amdgcn_sched_barrier(0);
  asm volatile("s_waitcnt lgkmcnt(0)" ::: "memory");
  __builtin_amdgcn_s_barrier();
  __builtin_amdgcn_sched_barrier(0);
}

// ---------------- embedding concat:  X[t][0..336) = [word(300) | pos(25) | 0pad] ----
__global__ void k_embed(const float* __restrict__ wv, const int* __restrict__ pidx,
                        const float* __restrict__ pemb, float* __restrict__ X) {
  int t = blockIdx.x;
  int pi = pidx[t];
  for (int c = threadIdx.x; c < 336; c += 128) {
    float v;
    if (c < 300)      v = wv[t * 300 + c];
    else if (c < 325) v = pemb[pi * 25 + (c - 300)];
    else              v = 0.f;
    X[t * 336 + c] = v;
  }
}

// ---------------- Wih rho-major repack: rho = u*4 + gate, zero-padded -------------
// src Wih [2][500][sK] (row = gate*125+u), bias b [2][500] ->
// Wp [2][512][dK], bp [2][512]
__global__ void k_wpack(const float* __restrict__ Wih, const float* __restrict__ b,
                        float* __restrict__ Wp, float* __restrict__ bp,
                        int sK, int dK) {
  const int d = blockIdx.y, rho = blockIdx.x;    // rho 0..511
  const int u = rho >> 2, g = rho & 3;
  const bool ok = (u < 125);
  const float* src = Wih + ((size_t)d * 500 + g * 125 + (ok ? u : 0)) * sK;
  float* dst = Wp + ((size_t)d * 512 + rho) * dK;
  for (int c = threadIdx.x; c < dK; c += 128)
    dst[c] = (ok && c < sK) ? src[c] : 0.f;
  if (threadIdx.x == 0)
    bp[d * 512 + rho] = ok ? b[d * 500 + g * 125 + u] : 0.f;
}

// ---------------- split fc1_W [100][500] -> Wab [200][256] ------------------------
__global__ void k_wab(const float* __restrict__ fc1W, float* __restrict__ Wab) {
  int r = blockIdx.x;                       // 0..199
  int sr = (r < 100) ? r : r - 100;
  int so = (r < 100) ? 0 : 250;
  for (int c = threadIdx.x; c < 256; c += 128)
    Wab[r * 256 + c] = (c < 250) ? fc1W[sr * 500 + so + c] : 0.f;
}

// ---------------- biasAB + sum(fc2_W) ----------------------------------------------
__global__ void k_misc(const float* __restrict__ fc1b, const float* __restrict__ fc2W,
                       float* __restrict__ biasAB, float* __restrict__ sumw) {
  __shared__ float red[128];
  int t = threadIdx.x;   // 128 threads
  for (int c = t; c < 256; c += 128)
    biasAB[c] = (c < 100) ? fc1b[c] : 0.f;
  float s = (t < 100) ? fc2W[t] : 0.f;
  red[t] = s; __syncthreads();
  for (int off = 64; off; off >>= 1) {
    if (t < off) red[t] += red[t + off];
    __syncthreads();
  }
  if (t == 0) sumw[0] = red[0];
}

// ---------------- tiled fp32 GEMM:  C = A @ B^T + bias -----------------------------
// A:[M][K], B:[N][K] (K mult of 16). transOut=0: C[m][n] (ldC=row len).
// transOut=1: C[n][m] (ldC = M), LDS-staged transpose for coalesced stores.
#define BM 64
#define BN 64
#define BKK 16
__global__ __launch_bounds__(256) void k_gemm(
    const float* __restrict__ A, const float* __restrict__ Bw,
    const float* __restrict__ bias, float* __restrict__ C,
    int M, int N, int K, int ldC, long sBz, long sCz, long sbz, int transOut) {
  const int z = blockIdx.z;
  const float* Bp = Bw + (size_t)z * sBz;
  const float* bp = bias + (size_t)z * sbz;
  float* Cp = C + (size_t)z * sCz;
  const int bm = blockIdx.y * BM, bn = blockIdx.x * BN;
  __shared__ __align__(16) float As[BKK][BM + 4];
  __shared__ __align__(16) float Bs[BKK][BN + 4];
  __shared__ float Ts[BN][BM + 1];
  const int tid = threadIdx.x;
  const int tx = tid & 15, ty = tid >> 4;
  const int lr = tid >> 2;            // 0..63
  const int lk = (tid & 3) * 4;       // 0,4,8,12
  float acc[4][4];
#pragma unroll
  for (int a = 0; a < 4; ++a)
#pragma unroll
    for (int b = 0; b < 4; ++b) acc[a][b] = 0.f;

  int brow = bn + lr; if (brow >= N) brow = N - 1;   // clamp (pad cols unused)
  for (int k0 = 0; k0 < K; k0 += BKK) {
    float4 a4 = *(const float4*)(A + (size_t)(bm + lr) * K + k0 + lk);
    float4 b4 = *(const float4*)(Bp + (size_t)brow * K + k0 + lk);
    __syncthreads();
    As[lk + 0][lr] = a4.x; As[lk + 1][lr] = a4.y; As[lk + 2][lr] = a4.z; As[lk + 3][lr] = a4.w;
    Bs[lk + 0][lr] = b4.x; Bs[lk + 1][lr] = b4.y; Bs[lk + 2][lr] = b4.z; Bs[lk + 3][lr] = b4.w;
    __syncthreads();
#pragma unroll
    for (int kk = 0; kk < BKK; ++kk) {
      float4 av = *(const float4*)&As[kk][ty * 4];
      float4 bv = *(const float4*)&Bs[kk][tx * 4];
      float aa[4] = {av.x, av.y, av.z, av.w};
      float bb[4] = {bv.x, bv.y, bv.z, bv.w};
#pragma unroll
      for (int a = 0; a < 4; ++a)
#pragma unroll
        for (int b = 0; b < 4; ++b)
          acc[a][b] = __builtin_fmaf(aa[a], bb[b], acc[a][b]);
    }
  }
  if (!transOut) {
#pragma unroll
    for (int a = 0; a < 4; ++a) {
      int i = bm + ty * 4 + a;
#pragma unroll
      for (int b = 0; b < 4; ++b) {
        int j = bn + tx * 4 + b;
        if (j < N) Cp[(size_t)i * ldC + j] = acc[a][b] + bp[j];
      }
    }
  } else {
    __syncthreads();
#pragma unroll
    for (int a = 0; a < 4; ++a)
#pragma unroll
      for (int b = 0; b < 4; ++b) {
        int jn = bn + tx * 4 + b; if (jn >= N) jn = N - 1;
        Ts[tx * 4 + b][ty * 4 + a] = acc[a][b] + bp[jn];
      }
    __syncthreads();
    const int n2 = tid >> 2, mq = (tid & 3) * 16;
    const int n = bn + n2;
    if (n < N) {
#pragma unroll
      for (int r = 0; r < 4; ++r) {
        int m0 = mq + r * 4;
        float4 v;
        v.x = Ts[n2][m0 + 0]; v.y = Ts[n2][m0 + 1];
        v.z = Ts[n2][m0 + 2]; v.w = Ts[n2][m0 + 3];
        *(float4*)(Cp + (size_t)n * ldC + bm + m0) = v;
      }
    }
  }
}

// ---------------- LSTM recurrence v7 (MFMA, 8 waves, minimal per-step overhead) ----
// v6 lesson: waves don't hide latency here (per-step barrier lockstep) — they only
// add redundant tail VALU. So: 8 waves (2/SIMD, the minimum that spreads the
// 128-MFMA/step across all SIMDs once: 620 cyc/SIMD floor), v5's verified fragment
// maps, and everything non-MFMA stripped:
//  - acc doubles as the pre-gate prefetch: after MFMA+select consume it, reload
//    acc from global Ptt for step s+1 (vmcnt rides the lgkm-only barrier).
//  - hist/flush deleted: writer lanes store hout directly (fire-and-forget).
//  - LDS = 512B h double-buffer only.
// rho = u*4+gate; A row = lc: rho=(w<<6)+(rt<<4)+lc; k = kt*32+lg*8+j;
// D: col=lc (replica), row=lg*4+reg -> acc[rt] regs = gates i,f,g,o of cell
// (w*16 + rt*4 + lg); lane tail-selects rt = q = lc>>2 (12 cndmask, static).
__global__ __launch_bounds__(512) void k_rec(const float* __restrict__ Ptt,
                                             const float* __restrict__ Whh,
                                             float* __restrict__ hout) {
  const int d = blockIdx.x;
  const bool fwd = (d == 0);
  const int t = threadIdx.x;
  const int w  = t >> 6;      // wave 0..7
  const int l  = t & 63;
  const int lg = l >> 4;      // k-group / D row-group
  const int lc = l & 15;      // A-row within tile / D column (replica)
  const int q  = lc >> 2;     // owned row-tile for the tail

  // ---- A fragments: a[rt][kt]; rho = w*64 + rt*16 + lc; k = kt*32 + lg*8 + j ----
  const float* Wd = Whh + (size_t)d * 500 * 125;
  f16x8 a[4][4];
#pragma unroll
  for (int rt = 0; rt < 4; ++rt) {
    const int rho = (w << 6) + (rt << 4) + lc;
    const int u2 = rho >> 2, g2 = rho & 3;
    const bool uok = (u2 < 125);
    const float* wr2 = Wd + (size_t)(g2 * 125 + (uok ? u2 : 0)) * 125;
#pragma unroll
    for (int kt = 0; kt < 4; ++kt) {
      f16x8 v;
#pragma unroll
      for (int j = 0; j < 8; ++j) {
        const int k = kt * 32 + lg * 8 + j;
        v[j] = (_Float16)((uok && k < 125) ? wr2[k] : 0.f);
      }
      a[rt][kt] = v;
    }
  }

  // ---- LDS: h double-buffer only (512 B) ----
  __shared__ __align__(16) _Float16 hf[2][128];
  if (t < 128) ((int*)hf)[t] = 0;

  // ---- global pre-gate stream: Ptt[d][time][512]; lane loads f32x4 at
  //      col w*64 + rt*16 + lg*4 (rows lg*4..+3 of tile rt) ----
  const int dstep = fwd ? 512 : -512;
  const float* pg = Ptt + (size_t)d * 1024 * 512 +
                    (size_t)(fwd ? 0 : 1023) * 512 + ((w << 6) + (lg << 2));
  f32x4 acc[4];
#pragma unroll
  for (int rt = 0; rt < 4; ++rt)
    acc[rt] = *(const f32x4*)(pg + rt * 16);
  pg += dstep;

  // ---- hout writer setup: lanes lc&3==0 own cell u_own ----
  const int u_own = (w << 4) + (q << 2) + lg;
  const bool wr = ((lc & 3) == 0) && (u_own < 125);
  float* ho = hout + (size_t)(fwd ? 0 : 1023) * 256 + d * 125 + u_own;
  const int hstep = fwd ? 256 : -256;

  float cst = 0.f;
  __syncthreads();

#pragma unroll 2
  for (int s = 0; s < 1024; ++s) {
    const int buf = s & 1;
    // ---- B fragments: h broadcast (same k-slot convention as A) ----
    f16x8 hfr[4];
#pragma unroll
    for (int kt = 0; kt < 4; ++kt)
      hfr[kt] = *(const f16x8*)&hf[buf][kt * 32 + lg * 8];
    // ---- 16 MFMAs; acc was pre-initialized with this step's pre-gates ----
#pragma unroll
    for (int kt = 0; kt < 4; ++kt)
#pragma unroll
      for (int rt = 0; rt < 4; ++rt)
        acc[rt] = __builtin_amdgcn_mfma_f32_16x16x32_f16(a[rt][kt], hfr[kt],
                                                         acc[rt], 0, 0, 0);
    // ---- extract owned tile, then recycle acc as next-step prefetch ----
    f32x4 T = (q == 0) ? acc[0] : (q == 1) ? acc[1] : (q == 2) ? acc[2] : acc[3];
#pragma unroll
    for (int rt = 0; rt < 4; ++rt)
      acc[rt] = *(const f32x4*)(pg + rt * 16);
    pg += dstep;
    // ---- full cell in-lane: gates i,f,g,o = T[0..3] ----
    float gi = frcp(1.f + fexp2(-LOG2E * T[0]));
    float gf = frcp(1.f + fexp2(-LOG2E * T[1]));
    float gg = __builtin_fmaf(2.f, frcp(1.f + fexp2(-2.f * LOG2E * T[2])), -1.f);
    float go = frcp(1.f + fexp2(-LOG2E * T[3]));
    cst = __builtin_fmaf(gf, cst, gi * gg);
    float th = __builtin_fmaf(2.f, frcp(1.f + fexp2(-2.f * LOG2E * cst)), -1.f);
    float hv = go * th;
    // ---- writers: h to LDS (next buf) + direct hout store ----
    if (wr) {
      hf[buf ^ 1][u_own] = (_Float16)hv;
      *ho = hv;
    }
    ho += hstep;
    lgkm_barrier();
  }
}

// ---------------- pairwise scorer ---------------------------------------------------
__global__ __launch_bounds__(256) void k_pair(const float* __restrict__ AB,
    const float* __restrict__ fc2W, const float* __restrict__ fc2b,
    const float* __restrict__ sumw, float* __restrict__ outS,
    float* __restrict__ scoresT) {
  __shared__ float As[32][100];
  __shared__ float Bs[32][101];
  __shared__ float w2s[100];
  const int tid = threadIdx.x;
  const int i0 = blockIdx.y * 32, j0 = blockIdx.x * 32;
  for (int idx = tid; idx < 3200; idx += 256) {
    int r = idx / 100, k = idx - r * 100;
    As[r][k] = AB[(size_t)(i0 + r) * 200 + k];
    Bs[r][k] = AB[(size_t)(j0 + r) * 200 + 100 + k];
  }
  if (tid < 100) w2s[tid] = 2.f * fc2W[tid];
  __syncthreads();
  const int tx = tid & 31, ty = tid >> 5;
  float acc[4] = {0.f, 0.f, 0.f, 0.f};
#pragma unroll 4
  for (int k = 0; k < 100; ++k) {
    float b = Bs[tx][k];
    float wk2 = w2s[k];
    float bs = b * (2.f * LOG2E);
#pragma unroll
    for (int q = 0; q < 4; ++q) {
      float a = As[ty + 8 * q][k];
      float r = frcp(1.f + fexp2(__builtin_fmaf(a, 2.f * LOG2E, bs)));
      acc[q] = __builtin_fmaf(wk2, r, acc[q]);
    }
  }
  float base = sumw[0] + fc2b[0];
  const int j = j0 + tx;
#pragma unroll
  for (int q = 0; q < 4; ++q) {
    int i = i0 + ty + 8 * q;
    float val = (i != j && j != 0) ? (base - acc[q]) : 0.f;
    outS[(size_t)i * 1024 + j] = val;
    scoresT[(size_t)j * 1024 + i] = val;
  }
}

// ---------------- per-child log-softmax contribution -------------------------------
__global__ __launch_bounds__(256) void k_soft(const float* __restrict__ scoresT,
    const int* __restrict__ parents, float* __restrict__ contrib) {
  const int j = blockIdx.x, tid = threadIdx.x;
  __shared__ float red[256];
  const float* row = scoresT + (size_t)j * 1024;
  float v0 = row[tid], v1 = row[tid + 256], v2 = row[tid + 512], v3 = row[tid + 768];
  float m = fmaxf(fmaxf(v0, v1), fmaxf(v2, v3));
  red[tid] = m; __syncthreads();
  for (int off = 128; off; off >>= 1) {
    if (tid < off) red[tid] = fmaxf(red[tid], red[tid + off]);
    __syncthreads();
  }
  m = red[0]; __syncthreads();
  float s = fexp2((v0 - m) * LOG2E) + fexp2((v1 - m) * LOG2E) +
            fexp2((v2 - m) * LOG2E) + fexp2((v3 - m) * LOG2E);
  red[tid] = s; __syncthreads();
  for (int off = 128; off; off >>= 1) {
    if (tid < off) red[tid] += red[tid + off];
    __syncthreads();
  }
  if (tid == 0) {
    float S = red[0];
    int p = parents[j];
    contrib[j] = row[p] - m - flog2(S) * LN2;
  }
}

__global__ __launch_bounds__(256) void k_loss(const float* __restrict__ contrib,
                                              float* __restrict__ out) {
  __shared__ float red[256];
  int tid = threadIdx.x;
  float s = contrib[tid] + contrib[tid + 256] + contrib[tid + 512] + contrib[tid + 768];
  red[tid] = s; __syncthreads();
  for (int off = 128; off; off >>= 1) {
    if (tid < off) red[tid] += red[tid + off];
    __syncthreads();
  }
  if (tid == 0) out[0] = -red[0] * (1.f / 1024.f);
}

// ---------------- launcher ---------------------------------------------------------
extern "C" void kernel_launch(void* const* d_in, const int* in_sizes, int n_in,
                              void* d_out, int out_size, void* d_ws, size_t ws_size,
                              hipStream_t stream) {
  const float* wv   = (const float*)d_in[0];
  const int*   pidx = (const int*)d_in[1];
  const int*   par  = (const int*)d_in[2];
  const float* pemb = (const float*)d_in[3];
  const float* Wih0 = (const float*)d_in[4];
  const float* Whh0 = (const float*)d_in[5];
  const float* b0   = (const float*)d_in[6];
  const float* Wih1 = (const float*)d_in[7];
  const float* Whh1 = (const float*)d_in[8];
  const float* b1   = (const float*)d_in[9];
  const float* fc1W = (const float*)d_in[10];
  const float* fc1b = (const float*)d_in[11];
  const float* fc2W = (const float*)d_in[12];
  const float* fc2b = (const float*)d_in[13];
  float* ws = (float*)d_ws;
  // workspace layout (float offsets)
  float* X      = ws + 0;        // 1024*336                      -> 344064
  float* Wih0p  = ws + 344064;   // 2*512*336 = 344064            -> 688128
  float* Wih1p  = ws + 688128;   // 2*512*256 = 262144            -> 950272
  float* brho0  = ws + 950272;   // 2*512                         -> 951296
  float* brho1  = ws + 951296;   // 2*512                         -> 952320
  float* Ptt    = ws + 952320;   // 2*1024*512 = 1048576 (shared layer0/1) -> 2000896
  float* h0     = ws + 2000896;  // 1024*256 = 262144             -> 2263040
  float* h1     = ws + 2263040;  // 1024*256 = 262144             -> 2525184
  float* Wab    = ws + 2525184;  // 200*256 = 51200               -> 2576384
  float* biasAB = ws + 2576384;  // 256                           -> 2576640
  float* AB     = ws + 2576640;  // 1024*200 = 204800             -> 2781440
  float* scT    = ws + 2781440;  // 1024*1024 = 1048576           -> 3830016
  float* contrib= ws + 3830016;  // 1024
  float* sumw   = ws + 3831040;  // 1
  float* out = (float*)d_out;

  // zero padded h buffers (cols 250..255 must stay 0 for the K=256 GEMMs)
  hipMemsetAsync(h0, 0, 1024 * 256 * sizeof(float), stream);
  hipMemsetAsync(h1, 0, 1024 * 256 * sizeof(float), stream);

  k_embed <<<1024, 128, 0, stream>>>(wv, pidx, pemb, X);
  k_wpack <<<dim3(512, 2), 128, 0, stream>>>(Wih0, b0, Wih0p, brho0, 325, 336);
  k_wpack <<<dim3(512, 2), 128, 0, stream>>>(Wih1, b1, Wih1p, brho1, 250, 256);
  k_wab   <<<200, 128, 0, stream>>>(fc1W, Wab);
  k_misc  <<<1, 128, 0, stream>>>(fc1b, fc2W, biasAB, sumw);

  // layer 0: pre-gates time-major rho-cols: Ptt[d][time][512]
  k_gemm<<<dim3(8, 16, 2), 256, 0, stream>>>(X, Wih0p, brho0, Ptt, 1024, 512, 336, 512,
                                             512L * 336, 1024L * 512, 512L, 0);
  k_rec <<<2, 512, 0, stream>>>(Ptt, Whh0, h0);
  // layer 1 (Ptt reused)
  k_gemm<<<dim3(8, 16, 2), 256, 0, stream>>>(h0, Wih1p, brho1, Ptt, 1024, 512, 256, 512,
                                             512L * 256, 1024L * 512, 512L, 0);
  k_rec <<<2, 512, 0, stream>>>(Ptt, Whh1, h1);
  // head/child projections (fc1_b folded into head half via biasAB)
  k_gemm<<<dim3(4, 16, 1), 256, 0, stream>>>(h1, Wab, biasAB, AB, 1024, 200, 256, 200,
                                             0L, 0L, 0L, 0);
  // pairwise scores + transposed copy
  k_pair<<<dim3(32, 32), 256, 0, stream>>>(AB, fc2W, fc2b, sumw, out + 1, scT);
  // per-child log-softmax and loss
  k_soft<<<1024, 256, 0, stream>>>(scT, par, contrib);
  k_loss<<<1, 256, 0, stream>>>(contrib, out);
}

// Round 9
// 1188.554 us; speedup vs baseline: 1.1121x; 1.1121x over previous
//
#include <hip/hip_runtime.h>

typedef float v2f __attribute__((ext_vector_type(2)));
typedef _Float16 f16x8 __attribute__((ext_vector_type(8)));
typedef float f32x4 __attribute__((ext_vector_type(4)));

#define LOG2E 1.4426950408889634f
#define LN2   0.6931471805599453f

__device__ __forceinline__ float fexp2(float x) {
  float r; asm("v_exp_f32 %0, %1" : "=v"(r) : "v"(x)); return r;
}
__device__ __forceinline__ float frcp(float x) {
  float r; asm("v_rcp_f32 %0, %1" : "=v"(r) : "v"(x)); return r;
}
__device__ __forceinline__ float flog2(float x) {
  float r; asm("v_log_f32 %0, %1" : "=v"(r) : "v"(x)); return r;
}
// LDS-ordering-only barrier: skips the vmcnt(0) drain __syncthreads would emit,
// so prefetched pre-gate loads / hout stores stay in flight across step barriers.
__device__ __forceinline__ void lgkm_barrier() {
  __builtin_amdgcn_sched_barrier(0);
  asm volatile("s_waitcnt lgkmcnt(0)" ::: "memory");
  __builtin_amdgcn_s_barrier();
  __builtin_amdgcn_sched_barrier(0);
}

// ---------------- embedding concat:  X[t][0..336) = [word(300) | pos(25) | 0pad] ----
__global__ void k_embed(const float* __restrict__ wv, const int* __restrict__ pidx,
                        const float* __restrict__ pemb, float* __restrict__ X) {
  int t = blockIdx.x;
  int pi = pidx[t];
  for (int c = threadIdx.x; c < 336; c += 128) {
    float v;
    if (c < 300)      v = wv[t * 300 + c];
    else if (c < 325) v = pemb[pi * 25 + (c - 300)];
    else              v = 0.f;
    X[t * 336 + c] = v;
  }
}

// ---------------- Wih rho-major repack: rho = u*4 + gate, zero-padded -------------
// src Wih [2][500][sK] (row = gate*125+u), bias b [2][500] ->
// Wp [2][512][dK], bp [2][512]
__global__ void k_wpack(const float* __restrict__ Wih, const float* __restrict__ b,
                        float* __restrict__ Wp, float* __restrict__ bp,
                        int sK, int dK) {
  const int d = blockIdx.y, rho = blockIdx.x;    // rho 0..511
  const int u = rho >> 2, g = rho & 3;
  const bool ok = (u < 125);
  const float* src = Wih + ((size_t)d * 500 + g * 125 + (ok ? u : 0)) * sK;
  float* dst = Wp + ((size_t)d * 512 + rho) * dK;
  for (int c = threadIdx.x; c < dK; c += 128)
    dst[c] = (ok && c < sK) ? src[c] : 0.f;
  if (threadIdx.x == 0)
    bp[d * 512 + rho] = ok ? b[d * 500 + g * 125 + u] : 0.f;
}

// ---------------- split fc1_W [100][500] -> Wab [200][256] ------------------------
__global__ void k_wab(const float* __restrict__ fc1W, float* __restrict__ Wab) {
  int r = blockIdx.x;                       // 0..199
  int sr = (r < 100) ? r : r - 100;
  int so = (r < 100) ? 0 : 250;
  for (int c = threadIdx.x; c < 256; c += 128)
    Wab[r * 256 + c] = (c < 250) ? fc1W[sr * 500 + so + c] : 0.f;
}

// ---------------- biasAB + sum(fc2_W) ----------------------------------------------
__global__ void k_misc(const float* __restrict__ fc1b, const float* __restrict__ fc2W,
                       float* __restrict__ biasAB, float* __restrict__ sumw) {
  __shared__ float red[128];
  int t = threadIdx.x;   // 128 threads
  for (int c = t; c < 256; c += 128)
    biasAB[c] = (c < 100) ? fc1b[c] : 0.f;
  float s = (t < 100) ? fc2W[t] : 0.f;
  red[t] = s; __syncthreads();
  for (int off = 64; off; off >>= 1) {
    if (t < off) red[t] += red[t + off];
    __syncthreads();
  }
  if (t == 0) sumw[0] = red[0];
}

// ---------------- tiled fp32 GEMM:  C = A @ B^T + bias -----------------------------
// A:[M][K], B:[N][K] (K mult of 16). transOut=0: C[m][n] (ldC=row len).
// transOut=1: C[n][m] (ldC = M), LDS-staged transpose for coalesced stores.
#define BM 64
#define BN 64
#define BKK 16
__global__ __launch_bounds__(256) void k_gemm(
    const float* __restrict__ A, const float* __restrict__ Bw,
    const float* __restrict__ bias, float* __restrict__ C,
    int M, int N, int K, int ldC, long sBz, long sCz, long sbz, int transOut) {
  const int z = blockIdx.z;
  const float* Bp = Bw + (size_t)z * sBz;
  const float* bp = bias + (size_t)z * sbz;
  float* Cp = C + (size_t)z * sCz;
  const int bm = blockIdx.y * BM, bn = blockIdx.x * BN;
  __shared__ __align__(16) float As[BKK][BM + 4];
  __shared__ __align__(16) float Bs[BKK][BN + 4];
  __shared__ float Ts[BN][BM + 1];
  const int tid = threadIdx.x;
  const int tx = tid & 15, ty = tid >> 4;
  const int lr = tid >> 2;            // 0..63
  const int lk = (tid & 3) * 4;       // 0,4,8,12
  float acc[4][4];
#pragma unroll
  for (int a = 0; a < 4; ++a)
#pragma unroll
    for (int b = 0; b < 4; ++b) acc[a][b] = 0.f;

  int brow = bn + lr; if (brow >= N) brow = N - 1;   // clamp (pad cols unused)
  for (int k0 = 0; k0 < K; k0 += BKK) {
    float4 a4 = *(const float4*)(A + (size_t)(bm + lr) * K + k0 + lk);
    float4 b4 = *(const float4*)(Bp + (size_t)brow * K + k0 + lk);
    __syncthreads();
    As[lk + 0][lr] = a4.x; As[lk + 1][lr] = a4.y; As[lk + 2][lr] = a4.z; As[lk + 3][lr] = a4.w;
    Bs[lk + 0][lr] = b4.x; Bs[lk + 1][lr] = b4.y; Bs[lk + 2][lr] = b4.z; Bs[lk + 3][lr] = b4.w;
    __syncthreads();
#pragma unroll
    for (int kk = 0; kk < BKK; ++kk) {
      float4 av = *(const float4*)&As[kk][ty * 4];
      float4 bv = *(const float4*)&Bs[kk][tx * 4];
      float aa[4] = {av.x, av.y, av.z, av.w};
      float bb[4] = {bv.x, bv.y, bv.z, bv.w};
#pragma unroll
      for (int a = 0; a < 4; ++a)
#pragma unroll
        for (int b = 0; b < 4; ++b)
          acc[a][b] = __builtin_fmaf(aa[a], bb[b], acc[a][b]);
    }
  }
  if (!transOut) {
#pragma unroll
    for (int a = 0; a < 4; ++a) {
      int i = bm + ty * 4 + a;
#pragma unroll
      for (int b = 0; b < 4; ++b) {
        int j = bn + tx * 4 + b;
        if (j < N) Cp[(size_t)i * ldC + j] = acc[a][b] + bp[j];
      }
    }
  } else {
    __syncthreads();
#pragma unroll
    for (int a = 0; a < 4; ++a)
#pragma unroll
      for (int b = 0; b < 4; ++b) {
        int jn = bn + tx * 4 + b; if (jn >= N) jn = N - 1;
        Ts[tx * 4 + b][ty * 4 + a] = acc[a][b] + bp[jn];
      }
    __syncthreads();
    const int n2 = tid >> 2, mq = (tid & 3) * 16;
    const int n = bn + n2;
    if (n < N) {
#pragma unroll
      for (int r = 0; r < 4; ++r) {
        int m0 = mq + r * 4;
        float4 v;
        v.x = Ts[n2][m0 + 0]; v.y = Ts[n2][m0 + 1];
        v.z = Ts[n2][m0 + 2]; v.w = Ts[n2][m0 + 3];
        *(float4*)(Cp + (size_t)n * ldC + bm + m0) = v;
      }
    }
  }
}

// ---------------- LSTM recurrence v8 (MFMA, zero-init acc, long-lead pre stream) ---
// v5/v6/v7 lead-time pattern: pre-gate load lead 8-step/1-step/0-step gave
// 525/545/575 us -> the global load latency must be multi-step-covered.
// v8: acc init = ZERO (no memory on the critical path); each lane's OWN cell
// pre-gates (contiguous f32x4 at Ptt[time][u_own*4]) are chunk-prefetched 4-8
// steps ahead (cur[4]/nxt[4] ring, the v5-proven pattern) and added to T after
// the select. MFMA replica tiles rt != q accumulate garbage harmlessly (zeroed
// each step anyway). Everything else = v7 (8 waves, direct hout stores, 512B LDS).
// NOTE: final chunk prefetch over-reads up to 4 rows past the stream end; for d=0
// that lands in d=1's half of Ptt, for d=1 it lands in the brho/Wihp region below
// Ptt — both inside the d_ws allocation, values discarded. No OOB outside d_ws.
__global__ __launch_bounds__(512) void k_rec(const float* __restrict__ Ptt,
                                             const float* __restrict__ Whh,
                                             float* __restrict__ hout) {
  const int d = blockIdx.x;
  const bool fwd = (d == 0);
  const int t = threadIdx.x;
  const int w  = t >> 6;      // wave 0..7
  const int l  = t & 63;
  const int lg = l >> 4;      // k-group / D row-group
  const int lc = l & 15;      // A-row within tile / D column (replica)
  const int q  = lc >> 2;     // owned row-tile for the tail

  // ---- A fragments: a[rt][kt]; rho = w*64 + rt*16 + lc; k = kt*32 + lg*8 + j ----
  const float* Wd = Whh + (size_t)d * 500 * 125;
  f16x8 a[4][4];
#pragma unroll
  for (int rt = 0; rt < 4; ++rt) {
    const int rho = (w << 6) + (rt << 4) + lc;
    const int u2 = rho >> 2, g2 = rho & 3;
    const bool uok = (u2 < 125);
    const float* wr2 = Wd + (size_t)(g2 * 125 + (uok ? u2 : 0)) * 125;
#pragma unroll
    for (int kt = 0; kt < 4; ++kt) {
      f16x8 v;
#pragma unroll
      for (int j = 0; j < 8; ++j) {
        const int k = kt * 32 + lg * 8 + j;
        v[j] = (_Float16)((uok && k < 125) ? wr2[k] : 0.f);
      }
      a[rt][kt] = v;
    }
  }

  // ---- LDS: h double-buffer only (512 B) ----
  __shared__ __align__(16) _Float16 hf[2][128];
  if (t < 128) ((int*)hf)[t] = 0;

  // ---- own-cell identity ----
  const int u_own = (w << 4) + (q << 2) + lg;          // 0..127 (>=125 inactive)
  const bool wr = ((lc & 3) == 0) && (u_own < 125);
  float* ho = hout + (size_t)(fwd ? 0 : 1023) * 256 + d * 125 + u_own;
  const int hstep = fwd ? 256 : -256;

  // ---- own-cell pre-gate stream: f32x4 at Ptt[d][time][u_own*4], +-1 row/step;
  //      chunk ring: cur[4]/nxt[4], prefetch lead 4-8 steps ----
  const int dstep = fwd ? 512 : -512;
  const float* pco = Ptt + (size_t)d * 1024 * 512 +
                     (size_t)(fwd ? 0 : 1023) * 512 + (u_own << 2);
  f32x4 cur0 = *(const f32x4*)(pco);
  f32x4 cur1 = *(const f32x4*)(pco + dstep);
  f32x4 cur2 = *(const f32x4*)(pco + 2 * dstep);
  f32x4 cur3 = *(const f32x4*)(pco + 3 * dstep);
  pco += 4 * dstep;

  f32x4 acc[4];
  const f32x4 z4 = {0.f, 0.f, 0.f, 0.f};
#pragma unroll
  for (int rt = 0; rt < 4; ++rt) acc[rt] = z4;

  float cst = 0.f;
  __syncthreads();

  for (int c = 0; c < 256; ++c) {
    // prefetch next chunk's pre-gates (4-8 step lead; vmcnt rides the barriers)
    f32x4 n0 = *(const f32x4*)(pco);
    f32x4 n1 = *(const f32x4*)(pco + dstep);
    f32x4 n2 = *(const f32x4*)(pco + 2 * dstep);
    f32x4 n3 = *(const f32x4*)(pco + 3 * dstep);
    pco += 4 * dstep;
#pragma unroll
    for (int e = 0; e < 4; ++e) {
      const int buf = e & 1;
      const f32x4 pre4 = (e == 0) ? cur0 : (e == 1) ? cur1 : (e == 2) ? cur2 : cur3;
      // ---- B fragments: h broadcast (same k-slot convention as A) ----
      f16x8 hfr[4];
#pragma unroll
      for (int kt = 0; kt < 4; ++kt)
        hfr[kt] = *(const f16x8*)&hf[buf][kt * 32 + lg * 8];
      // ---- 16 MFMAs on zero-initialized acc ----
#pragma unroll
      for (int kt = 0; kt < 4; ++kt)
#pragma unroll
        for (int rt = 0; rt < 4; ++rt)
          acc[rt] = __builtin_amdgcn_mfma_f32_16x16x32_f16(a[rt][kt], hfr[kt],
                                                           acc[rt], 0, 0, 0);
      // ---- extract own tile, re-zero acc, add pre-gates ----
      f32x4 T = (q == 0) ? acc[0] : (q == 1) ? acc[1] : (q == 2) ? acc[2] : acc[3];
#pragma unroll
      for (int rt = 0; rt < 4; ++rt) acc[rt] = z4;
      T += pre4;
      // ---- full cell in-lane: gates i,f,g,o = T[0..3] ----
      float gi = frcp(1.f + fexp2(-LOG2E * T[0]));
      float gf = frcp(1.f + fexp2(-LOG2E * T[1]));
      float gg = __builtin_fmaf(2.f, frcp(1.f + fexp2(-2.f * LOG2E * T[2])), -1.f);
      float go = frcp(1.f + fexp2(-LOG2E * T[3]));
      cst = __builtin_fmaf(gf, cst, gi * gg);
      float th = __builtin_fmaf(2.f, frcp(1.f + fexp2(-2.f * LOG2E * cst)), -1.f);
      float hv = go * th;
      // ---- writers: h to LDS (next buf) + direct hout store ----
      if (wr) {
        hf[buf ^ 1][u_own] = (_Float16)hv;
        *ho = hv;
      }
      ho += hstep;
      lgkm_barrier();
    }
    cur0 = n0; cur1 = n1; cur2 = n2; cur3 = n3;
  }
}

// ---------------- pairwise scorer ---------------------------------------------------
__global__ __launch_bounds__(256) void k_pair(const float* __restrict__ AB,
    const float* __restrict__ fc2W, const float* __restrict__ fc2b,
    const float* __restrict__ sumw, float* __restrict__ outS,
    float* __restrict__ scoresT) {
  __shared__ float As[32][100];
  __shared__ float Bs[32][101];
  __shared__ float w2s[100];
  const int tid = threadIdx.x;
  const int i0 = blockIdx.y * 32, j0 = blockIdx.x * 32;
  for (int idx = tid; idx < 3200; idx += 256) {
    int r = idx / 100, k = idx - r * 100;
    As[r][k] = AB[(size_t)(i0 + r) * 200 + k];
    Bs[r][k] = AB[(size_t)(j0 + r) * 200 + 100 + k];
  }
  if (tid < 100) w2s[tid] = 2.f * fc2W[tid];
  __syncthreads();
  const int tx = tid & 31, ty = tid >> 5;
  float acc[4] = {0.f, 0.f, 0.f, 0.f};
#pragma unroll 4
  for (int k = 0; k < 100; ++k) {
    float b = Bs[tx][k];
    float wk2 = w2s[k];
    float bs = b * (2.f * LOG2E);
#pragma unroll
    for (int q = 0; q < 4; ++q) {
      float a = As[ty + 8 * q][k];
      float r = frcp(1.f + fexp2(__builtin_fmaf(a, 2.f * LOG2E, bs)));
      acc[q] = __builtin_fmaf(wk2, r, acc[q]);
    }
  }
  float base = sumw[0] + fc2b[0];
  const int j = j0 + tx;
#pragma unroll
  for (int q = 0; q < 4; ++q) {
    int i = i0 + ty + 8 * q;
    float val = (i != j && j != 0) ? (base - acc[q]) : 0.f;
    outS[(size_t)i * 1024 + j] = val;
    scoresT[(size_t)j * 1024 + i] = val;
  }
}

// ---------------- per-child log-softmax contribution -------------------------------
__global__ __launch_bounds__(256) void k_soft(const float* __restrict__ scoresT,
    const int* __restrict__ parents, float* __restrict__ contrib) {
  const int j = blockIdx.x, tid = threadIdx.x;
  __shared__ float red[256];
  const float* row = scoresT + (size_t)j * 1024;
  float v0 = row[tid], v1 = row[tid + 256], v2 = row[tid + 512], v3 = row[tid + 768];
  float m = fmaxf(fmaxf(v0, v1), fmaxf(v2, v3));
  red[tid] = m; __syncthreads();
  for (int off = 128; off; off >>= 1) {
    if (tid < off) red[tid] = fmaxf(red[tid], red[tid + off]);
    __syncthreads();
  }
  m = red[0]; __syncthreads();
  float s = fexp2((v0 - m) * LOG2E) + fexp2((v1 - m) * LOG2E) +
            fexp2((v2 - m) * LOG2E) + fexp2((v3 - m) * LOG2E);
  red[tid] = s; __syncthreads();
  for (int off = 128; off; off >>= 1) {
    if (tid < off) red[tid] += red[tid + off];
    __syncthreads();
  }
  if (tid == 0) {
    float S = red[0];
    int p = parents[j];
    contrib[j] = row[p] - m - flog2(S) * LN2;
  }
}

__global__ __launch_bounds__(256) void k_loss(const float* __restrict__ contrib,
                                              float* __restrict__ out) {
  __shared__ float red[256];
  int tid = threadIdx.x;
  float s = contrib[tid] + contrib[tid + 256] + contrib[tid + 512] + contrib[tid + 768];
  red[tid] = s; __syncthreads();
  for (int off = 128; off; off >>= 1) {
    if (tid < off) red[tid] += red[tid + off];
    __syncthreads();
  }
  if (tid == 0) out[0] = -red[0] * (1.f / 1024.f);
}

// ---------------- launcher ---------------------------------------------------------
extern "C" void kernel_launch(void* const* d_in, const int* in_sizes, int n_in,
                              void* d_out, int out_size, void* d_ws, size_t ws_size,
                              hipStream_t stream) {
  const float* wv   = (const float*)d_in[0];
  const int*   pidx = (const int*)d_in[1];
  const int*   par  = (const int*)d_in[2];
  const float* pemb = (const float*)d_in[3];
  const float* Wih0 = (const float*)d_in[4];
  const float* Whh0 = (const float*)d_in[5];
  const float* b0   = (const float*)d_in[6];
  const float* Wih1 = (const float*)d_in[7];
  const float* Whh1 = (const float*)d_in[8];
  const float* b1   = (const float*)d_in[9];
  const float* fc1W = (const float*)d_in[10];
  const float* fc1b = (const float*)d_in[11];
  const float* fc2W = (const float*)d_in[12];
  const float* fc2b = (const float*)d_in[13];
  float* ws = (float*)d_ws;
  // workspace layout (float offsets)
  float* X      = ws + 0;        // 1024*336                      -> 344064
  float* Wih0p  = ws + 344064;   // 2*512*336 = 344064            -> 688128
  float* Wih1p  = ws + 688128;   // 2*512*256 = 262144            -> 950272
  float* brho0  = ws + 950272;   // 2*512                         -> 951296
  float* brho1  = ws + 951296;   // 2*512                         -> 952320
  float* Ptt    = ws + 952320;   // 2*1024*512 = 1048576 (shared layer0/1) -> 2000896
  float* h0     = ws + 2000896;  // 1024*256 = 262144             -> 2263040
  float* h1     = ws + 2263040;  // 1024*256 = 262144             -> 2525184
  float* Wab    = ws + 2525184;  // 200*256 = 51200               -> 2576384
  float* biasAB = ws + 2576384;  // 256                           -> 2576640
  float* AB     = ws + 2576640;  // 1024*200 = 204800             -> 2781440
  float* scT    = ws + 2781440;  // 1024*1024 = 1048576           -> 3830016
  float* contrib= ws + 3830016;  // 1024
  float* sumw   = ws + 3831040;  // 1
  float* out = (float*)d_out;

  // zero padded h buffers (cols 250..255 must stay 0 for the K=256 GEMMs)
  hipMemsetAsync(h0, 0, 1024 * 256 * sizeof(float), stream);
  hipMemsetAsync(h1, 0, 1024 * 256 * sizeof(float), stream);

  k_embed <<<1024, 128, 0, stream>>>(wv, pidx, pemb, X);
  k_wpack <<<dim3(512, 2), 128, 0, stream>>>(Wih0, b0, Wih0p, brho0, 325, 336);
  k_wpack <<<dim3(512, 2), 128, 0, stream>>>(Wih1, b1, Wih1p, brho1, 250, 256);
  k_wab   <<<200, 128, 0, stream>>>(fc1W, Wab);
  k_misc  <<<1, 128, 0, stream>>>(fc1b, fc2W, biasAB, sumw);

  // layer 0: pre-gates time-major rho-cols: Ptt[d][time][512]
  k_gemm<<<dim3(8, 16, 2), 256, 0, stream>>>(X, Wih0p, brho0, Ptt, 1024, 512, 336, 512,
                                             512L * 336, 1024L * 512, 512L, 0);
  k_rec <<<2, 512, 0, stream>>>(Ptt, Whh0, h0);
  // layer 1 (Ptt reused)
  k_gemm<<<dim3(8, 16, 2), 256, 0, stream>>>(h0, Wih1p, brho1, Ptt, 1024, 512, 256, 512,
                                             512L * 256, 1024L * 512, 512L, 0);
  k_rec <<<2, 512, 0, stream>>>(Ptt, Whh1, h1);
  // head/child projections (fc1_b folded into head half via biasAB)
  k_gemm<<<dim3(4, 16, 1), 256, 0, stream>>>(h1, Wab, biasAB, AB, 1024, 200, 256, 200,
                                             0L, 0L, 0L, 0);
  // pairwise scores + transposed copy
  k_pair<<<dim3(32, 32), 256, 0, stream>>>(AB, fc2W, fc2b, sumw, out + 1, scT);
  // per-child log-softmax and loss
  k_soft<<<1024, 256, 0, stream>>>(scT, par, contrib);
  k_loss<<<1, 256, 0, stream>>>(contrib, out);
}